// Round 1
// baseline (780.532 us; speedup 1.0000x reference)
//
#include <hip/hip_runtime.h>
#include <hip/hip_bf16.h>

#define FEAT 128

// ---------------- CSR build ----------------

__global__ __launch_bounds__(256) void count_deg(const int* __restrict__ dst, int E,
                                                 int* __restrict__ deg) {
    int e = blockIdx.x * 256 + threadIdx.x;
    if (e < E) atomicAdd(&deg[dst[e]], 1);
}

__global__ __launch_bounds__(256) void block_sum(const int* __restrict__ deg, int N,
                                                 int* __restrict__ bsum) {
    __shared__ int sm[256];
    int v = blockIdx.x * 256 + threadIdx.x;
    sm[threadIdx.x] = (v < N) ? deg[v] : 0;
    __syncthreads();
    for (int s = 128; s > 0; s >>= 1) {
        if (threadIdx.x < s) sm[threadIdx.x] += sm[threadIdx.x + s];
        __syncthreads();
    }
    if (threadIdx.x == 0) bsum[blockIdx.x] = sm[0];
}

__global__ void scan_bsum(int* bsum, int nblk) {
    if (threadIdx.x == 0 && blockIdx.x == 0) {
        int run = 0;
        for (int i = 0; i < nblk; ++i) { int t = bsum[i]; bsum[i] = run; run += t; }
    }
}

__global__ __launch_bounds__(256) void make_offsets(const int* __restrict__ deg,
                                                    const int* __restrict__ bsum, int N,
                                                    int* __restrict__ rowstart,
                                                    int* __restrict__ cursor,
                                                    float* __restrict__ dinv) {
    __shared__ int sm[256];
    int v = blockIdx.x * 256 + threadIdx.x;
    int d = (v < N) ? deg[v] : 0;
    sm[threadIdx.x] = d;
    __syncthreads();
    // Hillis-Steele inclusive scan (read-all-then-write via syncs)
    for (int off = 1; off < 256; off <<= 1) {
        int t = (threadIdx.x >= off) ? sm[threadIdx.x - off] : 0;
        __syncthreads();
        sm[threadIdx.x] += t;
        __syncthreads();
    }
    if (v < N) {
        int excl = sm[threadIdx.x] - d + bsum[blockIdx.x];
        rowstart[v] = excl;
        cursor[v]   = excl;
        dinv[v] = rsqrtf((float)d + 1.0f);   // +1 for self-loop
    }
}

__global__ __launch_bounds__(256) void fill_csr(const int* __restrict__ ei, int E,
                                                int* __restrict__ cursor,
                                                int* __restrict__ srcs) {
    int e = blockIdx.x * 256 + threadIdx.x;
    if (e < E) {
        int s = ei[e];          // src row
        int d = ei[E + e];      // dst row
        int pos = atomicAdd(&cursor[d], 1);
        srcs[pos] = s;
    }
}

// ---------------- dense GEMM: Y[N,128] = X[N,128] @ W[128,128] ----------------
// W staged in LDS (exactly 64KB). Each block: 32 rows; thread = 4 rows x 4 cols.

__global__ __launch_bounds__(256, 2) void gemm128(const float* __restrict__ X,
                                                  const float* __restrict__ W,
                                                  float* __restrict__ Y, int N) {
    __shared__ float Ws[128 * 128];
    {
        const float4* Wg = (const float4*)W;
        float4* Wl = (float4*)Ws;
        for (int i = threadIdx.x; i < 128 * 32; i += 256) Wl[i] = Wg[i];
    }
    __syncthreads();

    int rg = threadIdx.x >> 5;         // 0..7
    int cg = threadIdx.x & 31;         // 0..31
    int row0 = blockIdx.x * 32 + rg * 4;
    int c0 = cg * 4;

    const float* xp[4];
#pragma unroll
    for (int j = 0; j < 4; ++j) {
        int r = row0 + j; if (r >= N) r = N - 1;
        xp[j] = X + (size_t)r * FEAT;
    }

    float acc[4][4];
#pragma unroll
    for (int j = 0; j < 4; ++j)
#pragma unroll
        for (int c = 0; c < 4; ++c) acc[j][c] = 0.f;

    for (int k = 0; k < 128; k += 4) {
        float4 xr[4], wr[4];
#pragma unroll
        for (int j = 0; j < 4; ++j) xr[j] = *(const float4*)(xp[j] + k);
#pragma unroll
        for (int kk = 0; kk < 4; ++kk) wr[kk] = *(const float4*)(&Ws[(k + kk) * 128 + c0]);
#pragma unroll
        for (int j = 0; j < 4; ++j) {
            const float xv[4] = {xr[j].x, xr[j].y, xr[j].z, xr[j].w};
#pragma unroll
            for (int kk = 0; kk < 4; ++kk) {
                acc[j][0] += xv[kk] * wr[kk].x;
                acc[j][1] += xv[kk] * wr[kk].y;
                acc[j][2] += xv[kk] * wr[kk].z;
                acc[j][3] += xv[kk] * wr[kk].w;
            }
        }
    }

#pragma unroll
    for (int j = 0; j < 4; ++j) {
        int r = row0 + j;
        if (r < N) {
            float4 o = {acc[j][0], acc[j][1], acc[j][2], acc[j][3]};
            *(float4*)(Y + (size_t)r * FEAT + c0) = o;
        }
    }
}

// ---------------- aggregation + bias + ReLU (fused) ----------------
// One wave per node; lane holds float2 of the 128-wide feature row.
// H[v] = relu( dinv[v]^2 * Y[v] + sum_e dinv[s]*dinv[v]*Y[s] + b )

__global__ __launch_bounds__(256) void agg_relu(const float* __restrict__ Y,
                                                const float* __restrict__ dinv,
                                                const int* __restrict__ rowstart,
                                                const int* __restrict__ degc,
                                                const int* __restrict__ srcs,
                                                const float* __restrict__ bias,
                                                float* __restrict__ H, int N) {
    int wid  = (blockIdx.x * 256 + threadIdx.x) >> 6;
    int lane = threadIdx.x & 63;
    if (wid >= N) return;
    int v = wid;
    float dv = dinv[v];

    float2 yv = ((const float2*)(Y + (size_t)v * FEAT))[lane];
    float selfc = dv * dv;
    float accx = selfc * yv.x;
    float accy = selfc * yv.y;

    int base = rowstart[v];
    int n = degc[v];
    for (int i0 = 0; i0 < n; i0 += 64) {
        int m = n - i0; if (m > 64) m = 64;
        int sl = 0; float cl = 0.f;
        if (lane < m) {
            sl = srcs[base + i0 + lane];
            cl = dinv[sl] * dv;
        }
        for (int i = 0; i < m; ++i) {
            int s   = __shfl(sl, i);
            float c = __shfl(cl, i);
            float2 ys = ((const float2*)(Y + (size_t)s * FEAT))[lane];
            accx += c * ys.x;
            accy += c * ys.y;
        }
    }
    float2 b = ((const float2*)bias)[lane];
    float2 o;
    o.x = fmaxf(accx + b.x, 0.f);
    o.y = fmaxf(accy + b.y, 0.f);
    ((float2*)(H + (size_t)v * FEAT))[lane] = o;
}

// ---------------- pool (batch is sorted) + head ----------------

__global__ __launch_bounds__(256) void pool_out(const float* __restrict__ H,
                                                const int* __restrict__ batch, int N,
                                                const float* __restrict__ Wout,
                                                const float* __restrict__ bout,
                                                float* __restrict__ out) {
    int g = blockIdx.x;
    // lower_bound: first idx with batch[idx] >= key (batch sorted ascending)
    int lo = 0, hi = N;
    while (lo < hi) { int mid = (lo + hi) >> 1; if (batch[mid] < g) lo = mid + 1; else hi = mid; }
    int start = lo;
    lo = start; hi = N;
    while (lo < hi) { int mid = (lo + hi) >> 1; if (batch[mid] < g + 1) lo = mid + 1; else hi = mid; }
    int end = lo;

    int c = threadIdx.x & 127;
    int half = threadIdx.x >> 7;
    float s = 0.f;
    for (int v = start + half; v < end; v += 2) s += H[(size_t)v * FEAT + c];

    __shared__ float sm[256];
    sm[threadIdx.x] = s;
    __syncthreads();
    if (threadIdx.x < 128) {
        float tot = sm[threadIdx.x] + sm[threadIdx.x + 128];
        int cnt = end - start;
        float pooled = tot / (float)(cnt > 0 ? cnt : 1);
        sm[threadIdx.x] = pooled * Wout[c];
    }
    __syncthreads();
    for (int s2 = 64; s2 > 0; s2 >>= 1) {
        if (threadIdx.x < s2) sm[threadIdx.x] += sm[threadIdx.x + s2];
        __syncthreads();
    }
    if (threadIdx.x == 0) out[g] = sm[0] + bout[0];
}

// ---------------- driver ----------------

extern "C" void kernel_launch(void* const* d_in, const int* in_sizes, int n_in,
                              void* d_out, int out_size, void* d_ws, size_t ws_size,
                              hipStream_t stream) {
    const float* x    = (const float*)d_in[0];
    const int*   ei   = (const int*)d_in[1];   // [2,E] (int64 -> int32 by harness)
    const int*   batch= (const int*)d_in[2];
    const float* W1   = (const float*)d_in[3];
    const float* b1   = (const float*)d_in[4];
    const float* W2   = (const float*)d_in[5];
    const float* b2   = (const float*)d_in[6];
    const float* Wout = (const float*)d_in[7];
    const float* bout = (const float*)d_in[8];

    int N = in_sizes[0] / FEAT;
    int E = in_sizes[1] / 2;
    int G = out_size;

    char* ws = (char*)d_ws;
    size_t off = 0;
    auto alloc = [&](size_t bytes) -> void* {
        void* p = ws + off;
        off += (bytes + 255) & ~(size_t)255;
        return p;
    };
    float* bufA     = (float*)alloc((size_t)N * FEAT * 4);
    float* bufB     = (float*)alloc((size_t)N * FEAT * 4);
    float* dinv     = (float*)alloc((size_t)N * 4);
    int*   deg      = (int*)alloc((size_t)N * 4);
    int*   rowstart = (int*)alloc((size_t)N * 4);
    int*   cursor   = (int*)alloc((size_t)N * 4);
    int nblk = (N + 255) / 256;
    int*   bsum     = (int*)alloc((size_t)nblk * 4);
    int*   srcs     = (int*)alloc((size_t)E * 4);

    // CSR build (edges are constant but ws is re-poisoned each call)
    hipMemsetAsync(deg, 0, (size_t)N * 4, stream);
    count_deg<<<(E + 255) / 256, 256, 0, stream>>>(ei + E, E, deg);
    block_sum<<<nblk, 256, 0, stream>>>(deg, N, bsum);
    scan_bsum<<<1, 64, 0, stream>>>(bsum, nblk);
    make_offsets<<<nblk, 256, 0, stream>>>(deg, bsum, N, rowstart, cursor, dinv);
    fill_csr<<<(E + 255) / 256, 256, 0, stream>>>(ei, E, cursor, srcs);

    int gemm_grid = (N + 31) / 32;
    int agg_grid  = (N + 3) / 4;   // 4 waves (nodes) per 256-thread block

    // Layer 1
    gemm128<<<gemm_grid, 256, 0, stream>>>(x, W1, bufA, N);
    agg_relu<<<agg_grid, 256, 0, stream>>>(bufA, dinv, rowstart, deg, srcs, b1, bufB, N);
    // Layer 2
    gemm128<<<gemm_grid, 256, 0, stream>>>(bufB, W2, bufA, N);
    agg_relu<<<agg_grid, 256, 0, stream>>>(bufA, dinv, rowstart, deg, srcs, b2, bufB, N);
    // Pool + head
    pool_out<<<G, 256, 0, stream>>>(bufB, batch, N, Wout, bout, (float*)d_out);
}

// Round 2
// 712.075 us; speedup vs baseline: 1.0961x; 1.0961x over previous
//
#include <hip/hip_runtime.h>
#include <hip/hip_bf16.h>
#include <hip/hip_fp16.h>

#define FEAT 128

// ---------------- CSR build ----------------

__global__ __launch_bounds__(256) void count_deg(const int* __restrict__ dst, int E,
                                                 int* __restrict__ deg) {
    int e = blockIdx.x * 256 + threadIdx.x;
    if (e < E) atomicAdd(&deg[dst[e]], 1);
}

__global__ __launch_bounds__(256) void block_sum(const int* __restrict__ deg, int N,
                                                 int* __restrict__ bsum) {
    __shared__ int sm[256];
    int v = blockIdx.x * 256 + threadIdx.x;
    sm[threadIdx.x] = (v < N) ? deg[v] : 0;
    __syncthreads();
    for (int s = 128; s > 0; s >>= 1) {
        if (threadIdx.x < s) sm[threadIdx.x] += sm[threadIdx.x + s];
        __syncthreads();
    }
    if (threadIdx.x == 0) bsum[blockIdx.x] = sm[0];
}

// Parallel exclusive scan of bsum (nblk <= 1024) in one block.
__global__ __launch_bounds__(1024) void scan_bsum(int* bsum, int nblk) {
    __shared__ int sm[1024];
    int t = threadIdx.x;
    int v = (t < nblk) ? bsum[t] : 0;
    sm[t] = v;
    __syncthreads();
    for (int off = 1; off < 1024; off <<= 1) {
        int x = (t >= off) ? sm[t - off] : 0;
        __syncthreads();
        sm[t] += x;
        __syncthreads();
    }
    if (t < nblk) bsum[t] = sm[t] - v;   // exclusive
}

__global__ __launch_bounds__(256) void make_offsets(const int* __restrict__ deg,
                                                    const int* __restrict__ bsum, int N,
                                                    int* __restrict__ rowstart,
                                                    int* __restrict__ cursor,
                                                    float* __restrict__ dinv) {
    __shared__ int sm[256];
    int v = blockIdx.x * 256 + threadIdx.x;
    int d = (v < N) ? deg[v] : 0;
    sm[threadIdx.x] = d;
    __syncthreads();
    for (int off = 1; off < 256; off <<= 1) {
        int t = (threadIdx.x >= off) ? sm[threadIdx.x - off] : 0;
        __syncthreads();
        sm[threadIdx.x] += t;
        __syncthreads();
    }
    if (v < N) {
        int excl = sm[threadIdx.x] - d + bsum[blockIdx.x];
        rowstart[v] = excl;
        cursor[v]   = excl;
        dinv[v] = rsqrtf((float)d + 1.0f);   // +1 for self-loop
    }
}

__global__ __launch_bounds__(256) void fill_csr(const int* __restrict__ ei, int E,
                                                int* __restrict__ cursor,
                                                int* __restrict__ srcs) {
    int e = blockIdx.x * 256 + threadIdx.x;
    if (e < E) {
        int s = ei[e];          // src row
        int d = ei[E + e];      // dst row
        int pos = atomicAdd(&cursor[d], 1);
        srcs[pos] = s;
    }
}

// ---------------- dense GEMM: Y[N,128] = X[N,128] @ W[128,128] ----------------
// fp32 math; input fp32 or fp16; output fp16. W staged in LDS (64KB).

__device__ __forceinline__ void loadrow4(const float* p, float* o) {
    float4 v = *(const float4*)p;
    o[0] = v.x; o[1] = v.y; o[2] = v.z; o[3] = v.w;
}
__device__ __forceinline__ void loadrow4(const __half* p, float* o) {
    __half2 a = ((const __half2*)p)[0], b = ((const __half2*)p)[1];
    float2 fa = __half22float2(a), fb = __half22float2(b);
    o[0] = fa.x; o[1] = fa.y; o[2] = fb.x; o[3] = fb.y;
}

template <typename TIN>
__global__ __launch_bounds__(256, 2) void gemm128(const TIN* __restrict__ X,
                                                  const float* __restrict__ W,
                                                  __half* __restrict__ Y, int N) {
    __shared__ float Ws[128 * 128];
    {
        const float4* Wg = (const float4*)W;
        float4* Wl = (float4*)Ws;
        for (int i = threadIdx.x; i < 128 * 32; i += 256) Wl[i] = Wg[i];
    }
    __syncthreads();

    int rg = threadIdx.x >> 5;         // 0..7
    int cg = threadIdx.x & 31;         // 0..31
    int row0 = blockIdx.x * 32 + rg * 4;
    int c0 = cg * 4;

    const TIN* xp[4];
#pragma unroll
    for (int j = 0; j < 4; ++j) {
        int r = row0 + j; if (r >= N) r = N - 1;
        xp[j] = X + (size_t)r * FEAT;
    }

    float acc[4][4];
#pragma unroll
    for (int j = 0; j < 4; ++j)
#pragma unroll
        for (int c = 0; c < 4; ++c) acc[j][c] = 0.f;

    for (int k = 0; k < 128; k += 4) {
        float xr[4][4];
        float4 wr[4];
#pragma unroll
        for (int j = 0; j < 4; ++j) loadrow4(xp[j] + k, xr[j]);
#pragma unroll
        for (int kk = 0; kk < 4; ++kk) wr[kk] = *(const float4*)(&Ws[(k + kk) * 128 + c0]);
#pragma unroll
        for (int j = 0; j < 4; ++j) {
#pragma unroll
            for (int kk = 0; kk < 4; ++kk) {
                acc[j][0] += xr[j][kk] * wr[kk].x;
                acc[j][1] += xr[j][kk] * wr[kk].y;
                acc[j][2] += xr[j][kk] * wr[kk].z;
                acc[j][3] += xr[j][kk] * wr[kk].w;
            }
        }
    }

#pragma unroll
    for (int j = 0; j < 4; ++j) {
        int r = row0 + j;
        if (r < N) {
            union { __half2 h[2]; float2 f; } u;
            u.h[0] = __floats2half2_rn(acc[j][0], acc[j][1]);
            u.h[1] = __floats2half2_rn(acc[j][2], acc[j][3]);
            *(float2*)(Y + (size_t)r * FEAT + c0) = u.f;
        }
    }
}

// ---------------- aggregation + bias + ReLU (fused), fp16 features ----------------
// One wave per node; lane holds __half2 (2 feats) of the 128-wide row.
// H[v] = relu( dinv[v]^2 * Y[v] + sum_e dinv[s]*dinv[v]*Y[s] + b )

__global__ __launch_bounds__(256) void agg_relu(const __half* __restrict__ Y,
                                                const float* __restrict__ dinv,
                                                const int* __restrict__ rowstart,
                                                const int* __restrict__ degc,
                                                const int* __restrict__ srcs,
                                                const float* __restrict__ bias,
                                                __half* __restrict__ H, int N) {
    int wid  = (blockIdx.x * 256 + threadIdx.x) >> 6;
    int lane = threadIdx.x & 63;
    if (wid >= N) return;
    int v = wid;
    float dv = dinv[v];

    float2 yv = __half22float2(((const __half2*)(Y + (size_t)v * FEAT))[lane]);
    float selfc = dv * dv;
    float accx = selfc * yv.x;
    float accy = selfc * yv.y;

    int base = rowstart[v];
    int n = degc[v];
    for (int i0 = 0; i0 < n; i0 += 64) {
        int m = n - i0; if (m > 64) m = 64;
        int sl = 0; float cl = 0.f;
        if (lane < m) {
            sl = srcs[base + i0 + lane];
            cl = dinv[sl] * dv;
        }
        for (int i = 0; i < m; ++i) {
            int s   = __shfl(sl, i);
            float c = __shfl(cl, i);
            float2 ys = __half22float2(((const __half2*)(Y + (size_t)s * FEAT))[lane]);
            accx += c * ys.x;
            accy += c * ys.y;
        }
    }
    float2 b = ((const float2*)bias)[lane];
    ((__half2*)(H + (size_t)v * FEAT))[lane] =
        __floats2half2_rn(fmaxf(accx + b.x, 0.f), fmaxf(accy + b.y, 0.f));
}

// ---------------- pool (batch is sorted) + head ----------------

__global__ __launch_bounds__(256) void pool_out(const __half* __restrict__ H,
                                                const int* __restrict__ batch, int N,
                                                const float* __restrict__ Wout,
                                                const float* __restrict__ bout,
                                                float* __restrict__ out) {
    int g = blockIdx.x;
    int lo = 0, hi = N;
    while (lo < hi) { int mid = (lo + hi) >> 1; if (batch[mid] < g) lo = mid + 1; else hi = mid; }
    int start = lo;
    lo = start; hi = N;
    while (lo < hi) { int mid = (lo + hi) >> 1; if (batch[mid] < g + 1) lo = mid + 1; else hi = mid; }
    int end = lo;

    int c = threadIdx.x & 127;
    int half = threadIdx.x >> 7;
    float s = 0.f;
    for (int v = start + half; v < end; v += 2) s += __half2float(H[(size_t)v * FEAT + c]);

    __shared__ float sm[256];
    sm[threadIdx.x] = s;
    __syncthreads();
    if (threadIdx.x < 128) {
        float tot = sm[threadIdx.x] + sm[threadIdx.x + 128];
        int cnt = end - start;
        float pooled = tot / (float)(cnt > 0 ? cnt : 1);
        sm[threadIdx.x] = pooled * Wout[c];
    }
    __syncthreads();
    for (int s2 = 64; s2 > 0; s2 >>= 1) {
        if (threadIdx.x < s2) sm[threadIdx.x] += sm[threadIdx.x + s2];
        __syncthreads();
    }
    if (threadIdx.x == 0) out[g] = sm[0] + bout[0];
}

// ---------------- driver ----------------

extern "C" void kernel_launch(void* const* d_in, const int* in_sizes, int n_in,
                              void* d_out, int out_size, void* d_ws, size_t ws_size,
                              hipStream_t stream) {
    const float* x    = (const float*)d_in[0];
    const int*   ei   = (const int*)d_in[1];   // [2,E]
    const int*   batch= (const int*)d_in[2];
    const float* W1   = (const float*)d_in[3];
    const float* b1   = (const float*)d_in[4];
    const float* W2   = (const float*)d_in[5];
    const float* b2   = (const float*)d_in[6];
    const float* Wout = (const float*)d_in[7];
    const float* bout = (const float*)d_in[8];

    int N = in_sizes[0] / FEAT;
    int E = in_sizes[1] / 2;
    int G = out_size;

    char* ws = (char*)d_ws;
    size_t off = 0;
    auto alloc = [&](size_t bytes) -> void* {
        void* p = ws + off;
        off += (bytes + 255) & ~(size_t)255;
        return p;
    };
    __half* bufA    = (__half*)alloc((size_t)N * FEAT * 2);
    __half* bufB    = (__half*)alloc((size_t)N * FEAT * 2);
    float* dinv     = (float*)alloc((size_t)N * 4);
    int*   deg      = (int*)alloc((size_t)N * 4);
    int*   rowstart = (int*)alloc((size_t)N * 4);
    int*   cursor   = (int*)alloc((size_t)N * 4);
    int nblk = (N + 255) / 256;
    int*   bsum     = (int*)alloc((size_t)nblk * 4);
    int*   srcs     = (int*)alloc((size_t)E * 4);

    // CSR build (ws is re-poisoned each call, so rebuild every time)
    hipMemsetAsync(deg, 0, (size_t)N * 4, stream);
    count_deg<<<(E + 255) / 256, 256, 0, stream>>>(ei + E, E, deg);
    block_sum<<<nblk, 256, 0, stream>>>(deg, N, bsum);
    scan_bsum<<<1, 1024, 0, stream>>>(bsum, nblk);
    make_offsets<<<nblk, 256, 0, stream>>>(deg, bsum, N, rowstart, cursor, dinv);
    fill_csr<<<(E + 255) / 256, 256, 0, stream>>>(ei, E, cursor, srcs);

    int gemm_grid = (N + 31) / 32;
    int agg_grid  = (N + 3) / 4;   // 4 waves (nodes) per 256-thread block

    // Layer 1
    gemm128<float><<<gemm_grid, 256, 0, stream>>>(x, W1, bufA, N);
    agg_relu<<<agg_grid, 256, 0, stream>>>(bufA, dinv, rowstart, deg, srcs, b1, bufB, N);
    // Layer 2
    gemm128<__half><<<gemm_grid, 256, 0, stream>>>(bufB, W2, bufA, N);
    agg_relu<<<agg_grid, 256, 0, stream>>>(bufA, dinv, rowstart, deg, srcs, b2, bufB, N);
    // Pool + head
    pool_out<<<G, 256, 0, stream>>>(bufB, batch, N, Wout, bout, (float*)d_out);
}

// Round 3
// 596.189 us; speedup vs baseline: 1.3092x; 1.1944x over previous
//
#include <hip/hip_runtime.h>
#include <hip/hip_bf16.h>
#include <hip/hip_fp16.h>

#define FEAT 128
// Buckets: 256 nodes each (dst >> 8). N <= 131072 so src fits in 17 bits,
// packed edge = src | (dst & 255) << 17  (25 bits, one uint32).

// ---------------- CSR build, phase 1: bucket histogram ----------------

__global__ __launch_bounds__(256) void k_bucket_count(const int* __restrict__ dst, int E,
                                                      int* __restrict__ bucket_cnt, int nb) {
    __shared__ int hist[512];
    for (int i = threadIdx.x; i < nb; i += 256) hist[i] = 0;
    __syncthreads();
    for (int e = blockIdx.x * 256 + threadIdx.x; e < E; e += gridDim.x * 256)
        atomicAdd(&hist[dst[e] >> 8], 1);
    __syncthreads();
    for (int i = threadIdx.x; i < nb; i += 256)
        if (hist[i]) atomicAdd(&bucket_cnt[i], hist[i]);
}

__global__ __launch_bounds__(512) void k_scan_buckets(const int* __restrict__ bucket_cnt, int nb,
                                                      int* __restrict__ bucket_base,
                                                      int* __restrict__ bucket_cursor, int E) {
    __shared__ int sm[512];
    int t = threadIdx.x;
    int v = (t < nb) ? bucket_cnt[t] : 0;
    sm[t] = v;
    __syncthreads();
    for (int off = 1; off < 512; off <<= 1) {
        int x = (t >= off) ? sm[t - off] : 0;
        __syncthreads();
        sm[t] += x;
        __syncthreads();
    }
    if (t < nb) {
        int excl = sm[t] - v;
        bucket_base[t] = excl;
        bucket_cursor[t] = excl;
    }
    if (t == 0) bucket_base[nb] = E;
}

// ---------------- phase 2: partition edges into buckets (packed) ----------------

__global__ __launch_bounds__(256) void k_bin_fill(const int* __restrict__ ei, int E, int chunk,
                                                  int* __restrict__ bucket_cursor,
                                                  unsigned* __restrict__ binned, int nb) {
    __shared__ int hist[512];
    __shared__ int cursor[512];
    int start = blockIdx.x * chunk;
    int end = start + chunk; if (end > E) end = E;
    for (int i = threadIdx.x; i < nb; i += 256) hist[i] = 0;
    __syncthreads();
    for (int e = start + threadIdx.x; e < end; e += 256)
        atomicAdd(&hist[ei[E + e] >> 8], 1);
    __syncthreads();
    for (int i = threadIdx.x; i < nb; i += 256) {
        int h = hist[i];
        cursor[i] = h ? atomicAdd(&bucket_cursor[i], h) : 0;
    }
    __syncthreads();
    for (int e = start + threadIdx.x; e < end; e += 256) {
        int s = ei[e];
        int d = ei[E + e];
        int b = d >> 8;
        int pos = atomicAdd(&cursor[b], 1);
        binned[pos] = (unsigned)s | ((unsigned)(d & 255) << 17);
    }
}

// ---------------- phase 3a: per-bucket degree count (LDS atomics) ----------------

__global__ __launch_bounds__(256) void k_bucket_deg(const unsigned* __restrict__ binned,
                                                    const int* __restrict__ bucket_base,
                                                    int N, int* __restrict__ deg) {
    __shared__ int ld[256];
    int b = blockIdx.x;
    ld[threadIdx.x] = 0;
    __syncthreads();
    int s = bucket_base[b], e = bucket_base[b + 1];
    for (int i = s + threadIdx.x; i < e; i += 256)
        atomicAdd(&ld[binned[i] >> 17], 1);
    __syncthreads();
    int v = (b << 8) + threadIdx.x;
    if (v < N) deg[v] = ld[threadIdx.x];
}

// ---------------- global exclusive scan of deg -> rowstart ----------------

__global__ __launch_bounds__(256) void block_sum(const int* __restrict__ deg, int N,
                                                 int* __restrict__ bsum) {
    __shared__ int sm[256];
    int v = blockIdx.x * 256 + threadIdx.x;
    sm[threadIdx.x] = (v < N) ? deg[v] : 0;
    __syncthreads();
    for (int s = 128; s > 0; s >>= 1) {
        if (threadIdx.x < s) sm[threadIdx.x] += sm[threadIdx.x + s];
        __syncthreads();
    }
    if (threadIdx.x == 0) bsum[blockIdx.x] = sm[0];
}

__global__ __launch_bounds__(1024) void scan_bsum(int* bsum, int nblk) {
    __shared__ int sm[1024];
    int t = threadIdx.x;
    int v = (t < nblk) ? bsum[t] : 0;
    sm[t] = v;
    __syncthreads();
    for (int off = 1; off < 1024; off <<= 1) {
        int x = (t >= off) ? sm[t - off] : 0;
        __syncthreads();
        sm[t] += x;
        __syncthreads();
    }
    if (t < nblk) bsum[t] = sm[t] - v;   // exclusive
}

__global__ __launch_bounds__(256) void make_offsets(const int* __restrict__ deg,
                                                    const int* __restrict__ bsum, int N,
                                                    int* __restrict__ rowstart,
                                                    float* __restrict__ dinv) {
    __shared__ int sm[256];
    int v = blockIdx.x * 256 + threadIdx.x;
    int d = (v < N) ? deg[v] : 0;
    sm[threadIdx.x] = d;
    __syncthreads();
    for (int off = 1; off < 256; off <<= 1) {
        int t = (threadIdx.x >= off) ? sm[threadIdx.x - off] : 0;
        __syncthreads();
        sm[threadIdx.x] += t;
        __syncthreads();
    }
    if (v < N) {
        rowstart[v] = sm[threadIdx.x] - d + bsum[blockIdx.x];
        dinv[v] = rsqrtf((float)d + 1.0f);   // +1 for self-loop
    }
}

// ---------------- phase 3b: per-bucket CSR fill (LDS cursors, exclusive region) ----

__global__ __launch_bounds__(256) void k_csr_fill(const unsigned* __restrict__ binned,
                                                  const int* __restrict__ bucket_base,
                                                  const int* __restrict__ rowstart,
                                                  int N, int* __restrict__ srcs) {
    __shared__ int cur[256];
    int b = blockIdx.x;
    int v = (b << 8) + threadIdx.x;
    cur[threadIdx.x] = (v < N) ? rowstart[v] : 0;
    __syncthreads();
    int s = bucket_base[b], e = bucket_base[b + 1];
    for (int i = s + threadIdx.x; i < e; i += 256) {
        unsigned p = binned[i];
        int pos = atomicAdd(&cur[p >> 17], 1);
        srcs[pos] = (int)(p & 0x1FFFF);
    }
}

// ---------------- dense GEMM: Y[N,128] = X[N,128] @ W[128,128] ----------------

__device__ __forceinline__ void loadrow4(const float* p, float* o) {
    float4 v = *(const float4*)p;
    o[0] = v.x; o[1] = v.y; o[2] = v.z; o[3] = v.w;
}
__device__ __forceinline__ void loadrow4(const __half* p, float* o) {
    __half2 a = ((const __half2*)p)[0], b = ((const __half2*)p)[1];
    float2 fa = __half22float2(a), fb = __half22float2(b);
    o[0] = fa.x; o[1] = fa.y; o[2] = fb.x; o[3] = fb.y;
}

template <typename TIN>
__global__ __launch_bounds__(256, 2) void gemm128(const TIN* __restrict__ X,
                                                  const float* __restrict__ W,
                                                  __half* __restrict__ Y, int N) {
    __shared__ float Ws[128 * 128];
    {
        const float4* Wg = (const float4*)W;
        float4* Wl = (float4*)Ws;
        for (int i = threadIdx.x; i < 128 * 32; i += 256) Wl[i] = Wg[i];
    }
    __syncthreads();

    int rg = threadIdx.x >> 5;
    int cg = threadIdx.x & 31;
    int row0 = blockIdx.x * 32 + rg * 4;
    int c0 = cg * 4;

    const TIN* xp[4];
#pragma unroll
    for (int j = 0; j < 4; ++j) {
        int r = row0 + j; if (r >= N) r = N - 1;
        xp[j] = X + (size_t)r * FEAT;
    }

    float acc[4][4];
#pragma unroll
    for (int j = 0; j < 4; ++j)
#pragma unroll
        for (int c = 0; c < 4; ++c) acc[j][c] = 0.f;

    for (int k = 0; k < 128; k += 4) {
        float xr[4][4];
        float4 wr[4];
#pragma unroll
        for (int j = 0; j < 4; ++j) loadrow4(xp[j] + k, xr[j]);
#pragma unroll
        for (int kk = 0; kk < 4; ++kk) wr[kk] = *(const float4*)(&Ws[(k + kk) * 128 + c0]);
#pragma unroll
        for (int j = 0; j < 4; ++j) {
#pragma unroll
            for (int kk = 0; kk < 4; ++kk) {
                acc[j][0] += xr[j][kk] * wr[kk].x;
                acc[j][1] += xr[j][kk] * wr[kk].y;
                acc[j][2] += xr[j][kk] * wr[kk].z;
                acc[j][3] += xr[j][kk] * wr[kk].w;
            }
        }
    }

#pragma unroll
    for (int j = 0; j < 4; ++j) {
        int r = row0 + j;
        if (r < N) {
            union { __half2 h[2]; float2 f; } u;
            u.h[0] = __floats2half2_rn(acc[j][0], acc[j][1]);
            u.h[1] = __floats2half2_rn(acc[j][2], acc[j][3]);
            *(float2*)(Y + (size_t)r * FEAT + c0) = u.f;
        }
    }
}

// ---------------- aggregation + bias + ReLU (fused), fp16 features ----------------

__global__ __launch_bounds__(256) void agg_relu(const __half* __restrict__ Y,
                                                const float* __restrict__ dinv,
                                                const int* __restrict__ rowstart,
                                                const int* __restrict__ degc,
                                                const int* __restrict__ srcs,
                                                const float* __restrict__ bias,
                                                __half* __restrict__ H, int N) {
    int wid  = (blockIdx.x * 256 + threadIdx.x) >> 6;
    int lane = threadIdx.x & 63;
    if (wid >= N) return;
    int v = wid;
    float dv = dinv[v];

    float2 yv = __half22float2(((const __half2*)(Y + (size_t)v * FEAT))[lane]);
    float selfc = dv * dv;
    float accx = selfc * yv.x;
    float accy = selfc * yv.y;

    int base = rowstart[v];
    int n = degc[v];
    for (int i0 = 0; i0 < n; i0 += 64) {
        int m = n - i0; if (m > 64) m = 64;
        int sl = 0; float cl = 0.f;
        if (lane < m) {
            sl = srcs[base + i0 + lane];
            cl = dinv[sl] * dv;
        }
        for (int i = 0; i < m; ++i) {
            int s   = __shfl(sl, i);
            float c = __shfl(cl, i);
            float2 ys = __half22float2(((const __half2*)(Y + (size_t)s * FEAT))[lane]);
            accx += c * ys.x;
            accy += c * ys.y;
        }
    }
    float2 b = ((const float2*)bias)[lane];
    ((__half2*)(H + (size_t)v * FEAT))[lane] =
        __floats2half2_rn(fmaxf(accx + b.x, 0.f), fmaxf(accy + b.y, 0.f));
}

// ---------------- pool (batch is sorted) + head ----------------

__global__ __launch_bounds__(256) void pool_out(const __half* __restrict__ H,
                                                const int* __restrict__ batch, int N,
                                                const float* __restrict__ Wout,
                                                const float* __restrict__ bout,
                                                float* __restrict__ out) {
    int g = blockIdx.x;
    int lo = 0, hi = N;
    while (lo < hi) { int mid = (lo + hi) >> 1; if (batch[mid] < g) lo = mid + 1; else hi = mid; }
    int start = lo;
    lo = start; hi = N;
    while (lo < hi) { int mid = (lo + hi) >> 1; if (batch[mid] < g + 1) lo = mid + 1; else hi = mid; }
    int end = lo;

    int c = threadIdx.x & 127;
    int half = threadIdx.x >> 7;
    float s = 0.f;
    for (int v = start + half; v < end; v += 2) s += __half2float(H[(size_t)v * FEAT + c]);

    __shared__ float sm[256];
    sm[threadIdx.x] = s;
    __syncthreads();
    if (threadIdx.x < 128) {
        float tot = sm[threadIdx.x] + sm[threadIdx.x + 128];
        int cnt = end - start;
        float pooled = tot / (float)(cnt > 0 ? cnt : 1);
        sm[threadIdx.x] = pooled * Wout[c];
    }
    __syncthreads();
    for (int s2 = 64; s2 > 0; s2 >>= 1) {
        if (threadIdx.x < s2) sm[threadIdx.x] += sm[threadIdx.x + s2];
        __syncthreads();
    }
    if (threadIdx.x == 0) out[g] = sm[0] + bout[0];
}

// ---------------- driver ----------------

extern "C" void kernel_launch(void* const* d_in, const int* in_sizes, int n_in,
                              void* d_out, int out_size, void* d_ws, size_t ws_size,
                              hipStream_t stream) {
    const float* x    = (const float*)d_in[0];
    const int*   ei   = (const int*)d_in[1];   // [2,E]
    const int*   batch= (const int*)d_in[2];
    const float* W1   = (const float*)d_in[3];
    const float* b1   = (const float*)d_in[4];
    const float* W2   = (const float*)d_in[5];
    const float* b2   = (const float*)d_in[6];
    const float* Wout = (const float*)d_in[7];
    const float* bout = (const float*)d_in[8];

    int N = in_sizes[0] / FEAT;
    int E = in_sizes[1] / 2;
    int G = out_size;
    int nb = (N + 255) >> 8;          // buckets of 256 nodes (== scan block count)

    char* ws = (char*)d_ws;
    size_t off = 0;
    auto alloc = [&](size_t bytes) -> void* {
        void* p = ws + off;
        off += (bytes + 255) & ~(size_t)255;
        return p;
    };
    __half* bufA     = (__half*)alloc((size_t)N * FEAT * 2);
    __half* bufB     = (__half*)alloc((size_t)N * FEAT * 2);
    float* dinv      = (float*)alloc((size_t)N * 4);
    int*   deg       = (int*)alloc((size_t)N * 4);
    int*   rowstart  = (int*)alloc((size_t)N * 4);
    int*   bsum      = (int*)alloc((size_t)nb * 4);
    int*   bucket_cnt    = (int*)alloc((size_t)(nb + 1) * 4);
    int*   bucket_base   = (int*)alloc((size_t)(nb + 1) * 4);
    int*   bucket_cursor = (int*)alloc((size_t)nb * 4);
    unsigned* binned = (unsigned*)alloc((size_t)E * 4);
    int*   srcs      = (int*)alloc((size_t)E * 4);

    // ---- CSR build (rebuilt every call; ws is re-poisoned) ----
    hipMemsetAsync(bucket_cnt, 0, (size_t)nb * 4, stream);
    k_bucket_count<<<256, 256, 0, stream>>>(ei + E, E, bucket_cnt, nb);
    k_scan_buckets<<<1, 512, 0, stream>>>(bucket_cnt, nb, bucket_base, bucket_cursor, E);
    int chunk = (E + 127) / 128;
    k_bin_fill<<<128, 256, 0, stream>>>(ei, E, chunk, bucket_cursor, binned, nb);
    k_bucket_deg<<<nb, 256, 0, stream>>>(binned, bucket_base, N, deg);
    block_sum<<<nb, 256, 0, stream>>>(deg, N, bsum);
    scan_bsum<<<1, 1024, 0, stream>>>(bsum, nb);
    make_offsets<<<nb, 256, 0, stream>>>(deg, bsum, N, rowstart, dinv);
    k_csr_fill<<<nb, 256, 0, stream>>>(binned, bucket_base, rowstart, N, srcs);

    int gemm_grid = (N + 31) / 32;
    int agg_grid  = (N + 3) / 4;

    // Layer 1
    gemm128<float><<<gemm_grid, 256, 0, stream>>>(x, W1, bufA, N);
    agg_relu<<<agg_grid, 256, 0, stream>>>(bufA, dinv, rowstart, deg, srcs, b1, bufB, N);
    // Layer 2
    gemm128<__half><<<gemm_grid, 256, 0, stream>>>(bufB, W2, bufA, N);
    agg_relu<<<agg_grid, 256, 0, stream>>>(bufA, dinv, rowstart, deg, srcs, b2, bufB, N);
    // Pool + head
    pool_out<<<G, 256, 0, stream>>>(bufB, batch, N, Wout, bout, (float*)d_out);
}

// Round 4
// 506.436 us; speedup vs baseline: 1.5412x; 1.1772x over previous
//
#include <hip/hip_runtime.h>
#include <hip/hip_bf16.h>
#include <hip/hip_fp16.h>

#define FEAT 128
// Buckets: 256 nodes each (dst >> 8). N <= 131072 so src fits in 17 bits,
// packed edge = src | (dst & 255) << 17  (25 bits, one uint32).

// ---------------- CSR build, phase 1: bucket histogram ----------------

__global__ __launch_bounds__(256) void k_bucket_count(const int* __restrict__ dst, int E,
                                                      int* __restrict__ bucket_cnt, int nb) {
    __shared__ int hist[512];
    for (int i = threadIdx.x; i < nb; i += 256) hist[i] = 0;
    __syncthreads();
    for (int e = blockIdx.x * 256 + threadIdx.x; e < E; e += gridDim.x * 256)
        atomicAdd(&hist[dst[e] >> 8], 1);
    __syncthreads();
    for (int i = threadIdx.x; i < nb; i += 256)
        if (hist[i]) atomicAdd(&bucket_cnt[i], hist[i]);
}

__global__ __launch_bounds__(512) void k_scan_buckets(const int* __restrict__ bucket_cnt, int nb,
                                                      int* __restrict__ bucket_base,
                                                      int* __restrict__ bucket_cursor, int E) {
    __shared__ int sm[512];
    int t = threadIdx.x;
    int v = (t < nb) ? bucket_cnt[t] : 0;
    sm[t] = v;
    __syncthreads();
    for (int off = 1; off < 512; off <<= 1) {
        int x = (t >= off) ? sm[t - off] : 0;
        __syncthreads();
        sm[t] += x;
        __syncthreads();
    }
    if (t < nb) {
        int excl = sm[t] - v;
        bucket_base[t] = excl;
        bucket_cursor[t] = excl;
    }
    if (t == 0) bucket_base[nb] = E;
}

// ---------------- phase 2: partition edges into buckets (packed) ----------------

__global__ __launch_bounds__(256) void k_bin_fill(const int* __restrict__ ei, int E, int chunk,
                                                  int* __restrict__ bucket_cursor,
                                                  unsigned* __restrict__ binned, int nb) {
    __shared__ int hist[512];
    __shared__ int cursor[512];
    int start = blockIdx.x * chunk;
    int end = start + chunk; if (end > E) end = E;
    for (int i = threadIdx.x; i < nb; i += 256) hist[i] = 0;
    __syncthreads();
    for (int e = start + threadIdx.x; e < end; e += 256)
        atomicAdd(&hist[ei[E + e] >> 8], 1);
    __syncthreads();
    for (int i = threadIdx.x; i < nb; i += 256) {
        int h = hist[i];
        cursor[i] = h ? atomicAdd(&bucket_cursor[i], h) : 0;
    }
    __syncthreads();
    for (int e = start + threadIdx.x; e < end; e += 256) {
        int s = ei[e];
        int d = ei[E + e];
        int b = d >> 8;
        int pos = atomicAdd(&cursor[b], 1);
        binned[pos] = (unsigned)s | ((unsigned)(d & 255) << 17);
    }
}

// ---------------- phase 3a: per-bucket degree count (LDS atomics) ----------------

__global__ __launch_bounds__(256) void k_bucket_deg(const unsigned* __restrict__ binned,
                                                    const int* __restrict__ bucket_base,
                                                    int N, int* __restrict__ deg) {
    __shared__ int ld[256];
    int b = blockIdx.x;
    ld[threadIdx.x] = 0;
    __syncthreads();
    int s = bucket_base[b], e = bucket_base[b + 1];
    for (int i = s + threadIdx.x; i < e; i += 256)
        atomicAdd(&ld[binned[i] >> 17], 1);
    __syncthreads();
    int v = (b << 8) + threadIdx.x;
    if (v < N) deg[v] = ld[threadIdx.x];
}

// ---------------- global exclusive scan of deg -> rowstart ----------------

__global__ __launch_bounds__(256) void block_sum(const int* __restrict__ deg, int N,
                                                 int* __restrict__ bsum) {
    __shared__ int sm[256];
    int v = blockIdx.x * 256 + threadIdx.x;
    sm[threadIdx.x] = (v < N) ? deg[v] : 0;
    __syncthreads();
    for (int s = 128; s > 0; s >>= 1) {
        if (threadIdx.x < s) sm[threadIdx.x] += sm[threadIdx.x + s];
        __syncthreads();
    }
    if (threadIdx.x == 0) bsum[blockIdx.x] = sm[0];
}

__global__ __launch_bounds__(1024) void scan_bsum(int* bsum, int nblk) {
    __shared__ int sm[1024];
    int t = threadIdx.x;
    int v = (t < nblk) ? bsum[t] : 0;
    sm[t] = v;
    __syncthreads();
    for (int off = 1; off < 1024; off <<= 1) {
        int x = (t >= off) ? sm[t - off] : 0;
        __syncthreads();
        sm[t] += x;
        __syncthreads();
    }
    if (t < nblk) bsum[t] = sm[t] - v;   // exclusive
}

__global__ __launch_bounds__(256) void make_offsets(const int* __restrict__ deg,
                                                    const int* __restrict__ bsum, int N,
                                                    int* __restrict__ rowstart,
                                                    float* __restrict__ dinv) {
    __shared__ int sm[256];
    int v = blockIdx.x * 256 + threadIdx.x;
    int d = (v < N) ? deg[v] : 0;
    sm[threadIdx.x] = d;
    __syncthreads();
    for (int off = 1; off < 256; off <<= 1) {
        int t = (threadIdx.x >= off) ? sm[threadIdx.x - off] : 0;
        __syncthreads();
        sm[threadIdx.x] += t;
        __syncthreads();
    }
    if (v < N) {
        rowstart[v] = sm[threadIdx.x] - d + bsum[blockIdx.x];
        dinv[v] = rsqrtf((float)d + 1.0f);   // +1 for self-loop
    }
}

// ---- phase 3b: per-bucket CSR fill (LDS cursors) + per-edge (byte-offset, coeff) ----

__global__ __launch_bounds__(256) void k_csr_fill(const unsigned* __restrict__ binned,
                                                  const int* __restrict__ bucket_base,
                                                  const int* __restrict__ rowstart,
                                                  const float* __restrict__ dinv,
                                                  int N, int* __restrict__ soff,
                                                  float* __restrict__ coef) {
    __shared__ int cur[256];
    __shared__ float dv_l[256];
    int b = blockIdx.x;
    int v = (b << 8) + threadIdx.x;
    cur[threadIdx.x]  = (v < N) ? rowstart[v] : 0;
    dv_l[threadIdx.x] = (v < N) ? dinv[v] : 0.f;
    __syncthreads();
    int s = bucket_base[b], e = bucket_base[b + 1];
    for (int i = s + threadIdx.x; i < e; i += 256) {
        unsigned p = binned[i];
        int src = (int)(p & 0x1FFFF);
        int drl = (int)(p >> 17);              // dst within bucket
        int pos = atomicAdd(&cur[drl], 1);
        soff[pos] = src << 8;                  // byte offset of fp16 row (128*2 B)
        coef[pos] = dinv[src] * dv_l[drl];
    }
}

// ---------------- dense GEMM: Y[N,128] = X[N,128] @ W[128,128] ----------------

__device__ __forceinline__ void loadrow4(const float* p, float* o) {
    float4 v = *(const float4*)p;
    o[0] = v.x; o[1] = v.y; o[2] = v.z; o[3] = v.w;
}
__device__ __forceinline__ void loadrow4(const __half* p, float* o) {
    __half2 a = ((const __half2*)p)[0], b = ((const __half2*)p)[1];
    float2 fa = __half22float2(a), fb = __half22float2(b);
    o[0] = fa.x; o[1] = fa.y; o[2] = fb.x; o[3] = fb.y;
}

template <typename TIN>
__global__ __launch_bounds__(256, 2) void gemm128(const TIN* __restrict__ X,
                                                  const float* __restrict__ W,
                                                  __half* __restrict__ Y, int N) {
    __shared__ float Ws[128 * 128];
    {
        const float4* Wg = (const float4*)W;
        float4* Wl = (float4*)Ws;
        for (int i = threadIdx.x; i < 128 * 32; i += 256) Wl[i] = Wg[i];
    }
    __syncthreads();

    int rg = threadIdx.x >> 5;
    int cg = threadIdx.x & 31;
    int row0 = blockIdx.x * 32 + rg * 4;
    int c0 = cg * 4;

    const TIN* xp[4];
#pragma unroll
    for (int j = 0; j < 4; ++j) {
        int r = row0 + j; if (r >= N) r = N - 1;
        xp[j] = X + (size_t)r * FEAT;
    }

    float acc[4][4];
#pragma unroll
    for (int j = 0; j < 4; ++j)
#pragma unroll
        for (int c = 0; c < 4; ++c) acc[j][c] = 0.f;

    for (int k = 0; k < 128; k += 4) {
        float xr[4][4];
        float4 wr[4];
#pragma unroll
        for (int j = 0; j < 4; ++j) loadrow4(xp[j] + k, xr[j]);
#pragma unroll
        for (int kk = 0; kk < 4; ++kk) wr[kk] = *(const float4*)(&Ws[(k + kk) * 128 + c0]);
#pragma unroll
        for (int j = 0; j < 4; ++j) {
#pragma unroll
            for (int kk = 0; kk < 4; ++kk) {
                acc[j][0] += xr[j][kk] * wr[kk].x;
                acc[j][1] += xr[j][kk] * wr[kk].y;
                acc[j][2] += xr[j][kk] * wr[kk].z;
                acc[j][3] += xr[j][kk] * wr[kk].w;
            }
        }
    }

#pragma unroll
    for (int j = 0; j < 4; ++j) {
        int r = row0 + j;
        if (r < N) {
            union { __half2 h[2]; float2 f; } u;
            u.h[0] = __floats2half2_rn(acc[j][0], acc[j][1]);
            u.h[1] = __floats2half2_rn(acc[j][2], acc[j][3]);
            *(float2*)(Y + (size_t)r * FEAT + c0) = u.f;
        }
    }
}

// ---------------- aggregation + bias + ReLU (fused), fp16 features ----------------
// One wave per node; lane holds __half2 (2 feats). 4x unrolled edge loop:
// 4 independent 256B row loads in flight per wave iteration.

__global__ __launch_bounds__(256) void agg_relu(const __half* __restrict__ Y,
                                                const float* __restrict__ dinv,
                                                const int* __restrict__ rowstart,
                                                const int* __restrict__ degc,
                                                const int* __restrict__ soff,
                                                const float* __restrict__ coef,
                                                const float* __restrict__ bias,
                                                __half* __restrict__ H, int N) {
    int wid  = (blockIdx.x * 256 + threadIdx.x) >> 6;
    int lane = threadIdx.x & 63;
    if (wid >= N) return;
    int v = wid;
    float dv = dinv[v];

    const char* Yb = (const char*)Y;
    int lb = lane * 4;   // byte offset of this lane's __half2 within a row

    float2 yv = __half22float2(((const __half2*)(Y + (size_t)v * FEAT))[lane]);
    float selfc = dv * dv;
    float accx = selfc * yv.x;
    float accy = selfc * yv.y;

    int base = rowstart[v];
    int n = degc[v];
    for (int i0 = 0; i0 < n; i0 += 64) {
        int m = n - i0; if (m > 64) m = 64;
        int sl = 0; float cl = 0.f;
        if (lane < m) {
            sl = soff[base + i0 + lane];
            cl = coef[base + i0 + lane];
        }
        for (int i = 0; i < m; i += 4) {
            int o0 = __shfl(sl, i + 0), o1 = __shfl(sl, i + 1);
            int o2 = __shfl(sl, i + 2), o3 = __shfl(sl, i + 3);
            float c0 = __shfl(cl, i + 0), c1 = __shfl(cl, i + 1);
            float c2 = __shfl(cl, i + 2), c3 = __shfl(cl, i + 3);
            // 4 independent loads (tail lanes have c=0 and o=0 -> safe row 0)
            float2 y0 = __half22float2(*(const __half2*)(Yb + o0 + lb));
            float2 y1 = __half22float2(*(const __half2*)(Yb + o1 + lb));
            float2 y2 = __half22float2(*(const __half2*)(Yb + o2 + lb));
            float2 y3 = __half22float2(*(const __half2*)(Yb + o3 + lb));
            accx += c0 * y0.x; accy += c0 * y0.y;
            accx += c1 * y1.x; accy += c1 * y1.y;
            accx += c2 * y2.x; accy += c2 * y2.y;
            accx += c3 * y3.x; accy += c3 * y3.y;
        }
    }
    float2 b = ((const float2*)bias)[lane];
    ((__half2*)(H + (size_t)v * FEAT))[lane] =
        __floats2half2_rn(fmaxf(accx + b.x, 0.f), fmaxf(accy + b.y, 0.f));
}

// ---------------- pool (batch is sorted) + head ----------------

__global__ __launch_bounds__(256) void pool_out(const __half* __restrict__ H,
                                                const int* __restrict__ batch, int N,
                                                const float* __restrict__ Wout,
                                                const float* __restrict__ bout,
                                                float* __restrict__ out) {
    int g = blockIdx.x;
    int lo = 0, hi = N;
    while (lo < hi) { int mid = (lo + hi) >> 1; if (batch[mid] < g) lo = mid + 1; else hi = mid; }
    int start = lo;
    lo = start; hi = N;
    while (lo < hi) { int mid = (lo + hi) >> 1; if (batch[mid] < g + 1) lo = mid + 1; else hi = mid; }
    int end = lo;

    int c = threadIdx.x & 127;
    int half = threadIdx.x >> 7;
    float s = 0.f;
    for (int v = start + half; v < end; v += 2) s += __half2float(H[(size_t)v * FEAT + c]);

    __shared__ float sm[256];
    sm[threadIdx.x] = s;
    __syncthreads();
    if (threadIdx.x < 128) {
        float tot = sm[threadIdx.x] + sm[threadIdx.x + 128];
        int cnt = end - start;
        float pooled = tot / (float)(cnt > 0 ? cnt : 1);
        sm[threadIdx.x] = pooled * Wout[c];
    }
    __syncthreads();
    for (int s2 = 64; s2 > 0; s2 >>= 1) {
        if (threadIdx.x < s2) sm[threadIdx.x] += sm[threadIdx.x + s2];
        __syncthreads();
    }
    if (threadIdx.x == 0) out[g] = sm[0] + bout[0];
}

// ---------------- driver ----------------

extern "C" void kernel_launch(void* const* d_in, const int* in_sizes, int n_in,
                              void* d_out, int out_size, void* d_ws, size_t ws_size,
                              hipStream_t stream) {
    const float* x    = (const float*)d_in[0];
    const int*   ei   = (const int*)d_in[1];   // [2,E]
    const int*   batch= (const int*)d_in[2];
    const float* W1   = (const float*)d_in[3];
    const float* b1   = (const float*)d_in[4];
    const float* W2   = (const float*)d_in[5];
    const float* b2   = (const float*)d_in[6];
    const float* Wout = (const float*)d_in[7];
    const float* bout = (const float*)d_in[8];

    int N = in_sizes[0] / FEAT;
    int E = in_sizes[1] / 2;
    int G = out_size;
    int nb = (N + 255) >> 8;

    char* ws = (char*)d_ws;
    size_t off = 0;
    auto alloc = [&](size_t bytes) -> void* {
        void* p = ws + off;
        off += (bytes + 255) & ~(size_t)255;
        return p;
    };
    __half* bufA     = (__half*)alloc((size_t)N * FEAT * 2);
    __half* bufB     = (__half*)alloc((size_t)N * FEAT * 2);
    float* dinv      = (float*)alloc((size_t)N * 4);
    int*   deg       = (int*)alloc((size_t)N * 4);
    int*   rowstart  = (int*)alloc((size_t)N * 4);
    int*   bsum      = (int*)alloc((size_t)nb * 4);
    int*   bucket_cnt    = (int*)alloc((size_t)(nb + 1) * 4);
    int*   bucket_base   = (int*)alloc((size_t)(nb + 1) * 4);
    int*   bucket_cursor = (int*)alloc((size_t)nb * 4);
    unsigned* binned = (unsigned*)alloc((size_t)E * 4);
    int*   soff      = (int*)alloc((size_t)E * 4);
    float* coef      = (float*)alloc((size_t)E * 4);

    // ---- CSR build (rebuilt every call; ws is re-poisoned) ----
    hipMemsetAsync(bucket_cnt, 0, (size_t)nb * 4, stream);
    k_bucket_count<<<256, 256, 0, stream>>>(ei + E, E, bucket_cnt, nb);
    k_scan_buckets<<<1, 512, 0, stream>>>(bucket_cnt, nb, bucket_base, bucket_cursor, E);
    int chunk = (E + 127) / 128;
    k_bin_fill<<<128, 256, 0, stream>>>(ei, E, chunk, bucket_cursor, binned, nb);
    k_bucket_deg<<<nb, 256, 0, stream>>>(binned, bucket_base, N, deg);
    block_sum<<<nb, 256, 0, stream>>>(deg, N, bsum);
    scan_bsum<<<1, 1024, 0, stream>>>(bsum, nb);
    make_offsets<<<nb, 256, 0, stream>>>(deg, bsum, N, rowstart, dinv);
    k_csr_fill<<<nb, 256, 0, stream>>>(binned, bucket_base, rowstart, dinv, N, soff, coef);

    int gemm_grid = (N + 31) / 32;
    int agg_grid  = (N + 3) / 4;

    // Layer 1
    gemm128<float><<<gemm_grid, 256, 0, stream>>>(x, W1, bufA, N);
    agg_relu<<<agg_grid, 256, 0, stream>>>(bufA, dinv, rowstart, deg, soff, coef, b1, bufB, N);
    // Layer 2
    gemm128<__half><<<gemm_grid, 256, 0, stream>>>(bufB, W2, bufA, N);
    agg_relu<<<agg_grid, 256, 0, stream>>>(bufA, dinv, rowstart, deg, soff, coef, b2, bufB, N);
    // Pool + head
    pool_out<<<G, 256, 0, stream>>>(bufB, batch, N, Wout, bout, (float*)d_out);
}

// Round 5
// 386.758 us; speedup vs baseline: 2.0181x; 1.3094x over previous
//
#include <hip/hip_runtime.h>
#include <hip/hip_bf16.h>
#include <hip/hip_fp16.h>

#define FEAT 128
// Buckets: 256 nodes each (dst >> 8). N <= 131072 so src fits in 17 bits,
// packed edge = src | (dst & 255) << 17  (25 bits, one uint32).

typedef _Float16 h8 __attribute__((ext_vector_type(8)));
typedef float f4 __attribute__((ext_vector_type(4)));

// ---------------- CSR build, phase 1: bucket histogram ----------------

__global__ __launch_bounds__(256) void k_bucket_count(const int* __restrict__ dst, int E,
                                                      int* __restrict__ bucket_cnt, int nb) {
    __shared__ int hist[512];
    for (int i = threadIdx.x; i < nb; i += 256) hist[i] = 0;
    __syncthreads();
    for (int e = blockIdx.x * 256 + threadIdx.x; e < E; e += gridDim.x * 256)
        atomicAdd(&hist[dst[e] >> 8], 1);
    __syncthreads();
    for (int i = threadIdx.x; i < nb; i += 256)
        if (hist[i]) atomicAdd(&bucket_cnt[i], hist[i]);
}

__global__ __launch_bounds__(512) void k_scan_buckets(const int* __restrict__ bucket_cnt, int nb,
                                                      int* __restrict__ bucket_base,
                                                      int* __restrict__ bucket_cursor, int E) {
    __shared__ int sm[512];
    int t = threadIdx.x;
    int v = (t < nb) ? bucket_cnt[t] : 0;
    sm[t] = v;
    __syncthreads();
    for (int off = 1; off < 512; off <<= 1) {
        int x = (t >= off) ? sm[t - off] : 0;
        __syncthreads();
        sm[t] += x;
        __syncthreads();
    }
    if (t < nb) {
        int excl = sm[t] - v;
        bucket_base[t] = excl;
        bucket_cursor[t] = excl;
    }
    if (t == 0) bucket_base[nb] = E;
}

// ---------------- phase 2: partition edges into buckets (packed) ----------------

__global__ __launch_bounds__(256) void k_bin_fill(const int* __restrict__ ei, int E, int chunk,
                                                  int* __restrict__ bucket_cursor,
                                                  unsigned* __restrict__ binned, int nb) {
    __shared__ int hist[512];
    __shared__ int cursor[512];
    int start = blockIdx.x * chunk;
    int end = start + chunk; if (end > E) end = E;
    for (int i = threadIdx.x; i < nb; i += 256) hist[i] = 0;
    __syncthreads();
    for (int e = start + threadIdx.x; e < end; e += 256)
        atomicAdd(&hist[ei[E + e] >> 8], 1);
    __syncthreads();
    for (int i = threadIdx.x; i < nb; i += 256) {
        int h = hist[i];
        cursor[i] = h ? atomicAdd(&bucket_cursor[i], h) : 0;
    }
    __syncthreads();
    for (int e = start + threadIdx.x; e < end; e += 256) {
        int s = ei[e];
        int d = ei[E + e];
        int b = d >> 8;
        int pos = atomicAdd(&cursor[b], 1);
        binned[pos] = (unsigned)s | ((unsigned)(d & 255) << 17);
    }
}

// ---------------- phase 3a: per-bucket degree count (LDS atomics) ----------------

__global__ __launch_bounds__(256) void k_bucket_deg(const unsigned* __restrict__ binned,
                                                    const int* __restrict__ bucket_base,
                                                    int N, int* __restrict__ deg) {
    __shared__ int ld[256];
    int b = blockIdx.x;
    ld[threadIdx.x] = 0;
    __syncthreads();
    int s = bucket_base[b], e = bucket_base[b + 1];
    for (int i = s + threadIdx.x; i < e; i += 256)
        atomicAdd(&ld[binned[i] >> 17], 1);
    __syncthreads();
    int v = (b << 8) + threadIdx.x;
    if (v < N) deg[v] = ld[threadIdx.x];
}

// ---------------- global exclusive scan of deg -> rowstart ----------------

__global__ __launch_bounds__(256) void block_sum(const int* __restrict__ deg, int N,
                                                 int* __restrict__ bsum) {
    __shared__ int sm[256];
    int v = blockIdx.x * 256 + threadIdx.x;
    sm[threadIdx.x] = (v < N) ? deg[v] : 0;
    __syncthreads();
    for (int s = 128; s > 0; s >>= 1) {
        if (threadIdx.x < s) sm[threadIdx.x] += sm[threadIdx.x + s];
        __syncthreads();
    }
    if (threadIdx.x == 0) bsum[blockIdx.x] = sm[0];
}

__global__ __launch_bounds__(1024) void scan_bsum(int* bsum, int nblk) {
    __shared__ int sm[1024];
    int t = threadIdx.x;
    int v = (t < nblk) ? bsum[t] : 0;
    sm[t] = v;
    __syncthreads();
    for (int off = 1; off < 1024; off <<= 1) {
        int x = (t >= off) ? sm[t - off] : 0;
        __syncthreads();
        sm[t] += x;
        __syncthreads();
    }
    if (t < nblk) bsum[t] = sm[t] - v;   // exclusive
}

__global__ __launch_bounds__(256) void make_offsets(const int* __restrict__ deg,
                                                    const int* __restrict__ bsum, int N,
                                                    int* __restrict__ rowstart,
                                                    float* __restrict__ dinv) {
    __shared__ int sm[256];
    int v = blockIdx.x * 256 + threadIdx.x;
    int d = (v < N) ? deg[v] : 0;
    sm[threadIdx.x] = d;
    __syncthreads();
    for (int off = 1; off < 256; off <<= 1) {
        int t = (threadIdx.x >= off) ? sm[threadIdx.x - off] : 0;
        __syncthreads();
        sm[threadIdx.x] += t;
        __syncthreads();
    }
    if (v < N) {
        rowstart[v] = sm[threadIdx.x] - d + bsum[blockIdx.x];
        dinv[v] = rsqrtf((float)d + 1.0f);   // +1 for self-loop
    }
}

// ---- phase 3b: per-bucket CSR fill (LDS cursors) + per-edge (byte-offset, coeff) ----

__global__ __launch_bounds__(256) void k_csr_fill(const unsigned* __restrict__ binned,
                                                  const int* __restrict__ bucket_base,
                                                  const int* __restrict__ rowstart,
                                                  const float* __restrict__ dinv,
                                                  int N, int* __restrict__ soff,
                                                  float* __restrict__ coef) {
    __shared__ int cur[256];
    __shared__ float dv_l[256];
    int b = blockIdx.x;
    int v = (b << 8) + threadIdx.x;
    cur[threadIdx.x]  = (v < N) ? rowstart[v] : 0;
    dv_l[threadIdx.x] = (v < N) ? dinv[v] : 0.f;
    __syncthreads();
    int s = bucket_base[b], e = bucket_base[b + 1];
    for (int i = s + threadIdx.x; i < e; i += 256) {
        unsigned p = binned[i];
        int src = (int)(p & 0x1FFFF);
        int drl = (int)(p >> 17);              // dst within bucket
        int pos = atomicAdd(&cur[drl], 1);
        soff[pos] = src << 8;                  // byte offset of fp16 row (128*2 B)
        coef[pos] = dinv[src] * dv_l[drl];
    }
}

// ---------------- W pre-transpose + cast: Wt[n][k] = (half)W[k][n] ----------------

__global__ __launch_bounds__(256) void k_wt(const float* __restrict__ W,
                                            __half* __restrict__ Wt) {
    int t = blockIdx.x * 256 + threadIdx.x;    // 8192 threads total
    int n = t >> 6, k2 = (t & 63) * 2;
    float a = W[(size_t)k2 * 128 + n];
    float b = W[(size_t)(k2 + 1) * 128 + n];
    ((__half2*)Wt)[n * 64 + (k2 >> 1)] = __floats2half2_rn(a, b);
}

// ---------------- MFMA GEMM: Y[N,128] = X[N,128] @ W[128,128], fp16 in/out ----------
// Block = 4 waves x 16 rows = 64 rows, all 128 cols. Wt (transposed W) staged in
// LDS with XOR chunk-swizzle (chunk ^ (n&15)) -> conflict-free ds_read_b128.
// A-frag: A[m=lane&15][k=quad*8+j]; C: col=lane&15, row=quad*4+reg (m89/m120).

__device__ __forceinline__ void loadA(const __half* p, int quad, h8* a) {
#pragma unroll
    for (int ks = 0; ks < 4; ++ks)
        a[ks] = *(const h8*)(p + ks * 32 + quad * 8);
}
__device__ __forceinline__ void loadA(const float* p, int quad, h8* a) {
#pragma unroll
    for (int ks = 0; ks < 4; ++ks) {
        const float* q = p + ks * 32 + quad * 8;
        float4 f0 = *(const float4*)q;
        float4 f1 = *(const float4*)(q + 4);
        h8 v;
        v[0] = (_Float16)f0.x; v[1] = (_Float16)f0.y;
        v[2] = (_Float16)f0.z; v[3] = (_Float16)f0.w;
        v[4] = (_Float16)f1.x; v[5] = (_Float16)f1.y;
        v[6] = (_Float16)f1.z; v[7] = (_Float16)f1.w;
        a[ks] = v;
    }
}

template <typename TIN>
__global__ __launch_bounds__(256) void gemm_mfma(const TIN* __restrict__ X,
                                                 const __half* __restrict__ Wt,
                                                 __half* __restrict__ Y, int N) {
    __shared__ _Float16 Bs[128 * 128];   // [n][swizzled chunk][8 halves]
    {
        const float4* src = (const float4*)Wt;      // 2048 x 16B chunks
        float4* dst = (float4*)Bs;
        for (int i = threadIdx.x; i < 2048; i += 256) {
            int n = i >> 4, ch = i & 15;
            dst[n * 16 + (ch ^ (n & 15))] = src[i];
        }
    }
    __syncthreads();

    int lane = threadIdx.x & 63;
    int wave = threadIdx.x >> 6;
    int m = lane & 15;
    int quad = lane >> 4;
    int row0 = blockIdx.x * 64 + wave * 16;

    int rA = row0 + m; if (rA >= N) rA = N - 1;
    h8 a[4];
    loadA(X + (size_t)rA * FEAT, quad, a);

    f4 acc[8];
#pragma unroll
    for (int nt = 0; nt < 8; ++nt) acc[nt] = (f4){0.f, 0.f, 0.f, 0.f};

#pragma unroll
    for (int nt = 0; nt < 8; ++nt) {
        const _Float16* bbase = Bs + (nt * 16 + m) * 128;
#pragma unroll
        for (int ks = 0; ks < 4; ++ks) {
            int ch = (ks * 4 + quad) ^ m;
            h8 b = *(const h8*)(bbase + ch * 8);
            acc[nt] = __builtin_amdgcn_mfma_f32_16x16x32_f16(a[ks], b, acc[nt], 0, 0, 0);
        }
    }

#pragma unroll
    for (int nt = 0; nt < 8; ++nt) {
#pragma unroll
        for (int r = 0; r < 4; ++r) {
            int row = row0 + quad * 4 + r;
            if (row < N)
                Y[(size_t)row * FEAT + nt * 16 + m] = __float2half(acc[nt][r]);
        }
    }
}

// ---------------- aggregation + bias + ReLU (fused), fp16 features ----------------

__global__ __launch_bounds__(256) void agg_relu(const __half* __restrict__ Y,
                                                const float* __restrict__ dinv,
                                                const int* __restrict__ rowstart,
                                                const int* __restrict__ degc,
                                                const int* __restrict__ soff,
                                                const float* __restrict__ coef,
                                                const float* __restrict__ bias,
                                                __half* __restrict__ H, int N) {
    int wid  = (blockIdx.x * 256 + threadIdx.x) >> 6;
    int lane = threadIdx.x & 63;
    if (wid >= N) return;
    int v = wid;
    float dv = dinv[v];

    const char* Yb = (const char*)Y;
    int lb = lane * 4;   // byte offset of this lane's __half2 within a row

    float2 yv = __half22float2(((const __half2*)(Y + (size_t)v * FEAT))[lane]);
    float selfc = dv * dv;
    float accx = selfc * yv.x;
    float accy = selfc * yv.y;

    int base = rowstart[v];
    int n = degc[v];
    for (int i0 = 0; i0 < n; i0 += 64) {
        int m = n - i0; if (m > 64) m = 64;
        int sl = 0; float cl = 0.f;
        if (lane < m) {
            sl = soff[base + i0 + lane];
            cl = coef[base + i0 + lane];
        }
        for (int i = 0; i < m; i += 4) {
            int o0 = __shfl(sl, i + 0), o1 = __shfl(sl, i + 1);
            int o2 = __shfl(sl, i + 2), o3 = __shfl(sl, i + 3);
            float c0 = __shfl(cl, i + 0), c1 = __shfl(cl, i + 1);
            float c2 = __shfl(cl, i + 2), c3 = __shfl(cl, i + 3);
            float2 y0 = __half22float2(*(const __half2*)(Yb + o0 + lb));
            float2 y1 = __half22float2(*(const __half2*)(Yb + o1 + lb));
            float2 y2 = __half22float2(*(const __half2*)(Yb + o2 + lb));
            float2 y3 = __half22float2(*(const __half2*)(Yb + o3 + lb));
            accx += c0 * y0.x; accy += c0 * y0.y;
            accx += c1 * y1.x; accy += c1 * y1.y;
            accx += c2 * y2.x; accy += c2 * y2.y;
            accx += c3 * y3.x; accy += c3 * y3.y;
        }
    }
    float2 b = ((const float2*)bias)[lane];
    ((__half2*)(H + (size_t)v * FEAT))[lane] =
        __floats2half2_rn(fmaxf(accx + b.x, 0.f), fmaxf(accy + b.y, 0.f));
}

// ---------------- pool (batch is sorted) + head ----------------

__global__ __launch_bounds__(256) void pool_out(const __half* __restrict__ H,
                                                const int* __restrict__ batch, int N,
                                                const float* __restrict__ Wout,
                                                const float* __restrict__ bout,
                                                float* __restrict__ out) {
    int g = blockIdx.x;
    int lo = 0, hi = N;
    while (lo < hi) { int mid = (lo + hi) >> 1; if (batch[mid] < g) lo = mid + 1; else hi = mid; }
    int start = lo;
    lo = start; hi = N;
    while (lo < hi) { int mid = (lo + hi) >> 1; if (batch[mid] < g + 1) lo = mid + 1; else hi = mid; }
    int end = lo;

    int c = threadIdx.x & 127;
    int half = threadIdx.x >> 7;
    float s = 0.f;
    for (int v = start + half; v < end; v += 2) s += __half2float(H[(size_t)v * FEAT + c]);

    __shared__ float sm[256];
    sm[threadIdx.x] = s;
    __syncthreads();
    if (threadIdx.x < 128) {
        float tot = sm[threadIdx.x] + sm[threadIdx.x + 128];
        int cnt = end - start;
        float pooled = tot / (float)(cnt > 0 ? cnt : 1);
        sm[threadIdx.x] = pooled * Wout[c];
    }
    __syncthreads();
    for (int s2 = 64; s2 > 0; s2 >>= 1) {
        if (threadIdx.x < s2) sm[threadIdx.x] += sm[threadIdx.x + s2];
        __syncthreads();
    }
    if (threadIdx.x == 0) out[g] = sm[0] + bout[0];
}

// ---------------- driver ----------------

extern "C" void kernel_launch(void* const* d_in, const int* in_sizes, int n_in,
                              void* d_out, int out_size, void* d_ws, size_t ws_size,
                              hipStream_t stream) {
    const float* x    = (const float*)d_in[0];
    const int*   ei   = (const int*)d_in[1];   // [2,E]
    const int*   batch= (const int*)d_in[2];
    const float* W1   = (const float*)d_in[3];
    const float* b1   = (const float*)d_in[4];
    const float* W2   = (const float*)d_in[5];
    const float* b2   = (const float*)d_in[6];
    const float* Wout = (const float*)d_in[7];
    const float* bout = (const float*)d_in[8];

    int N = in_sizes[0] / FEAT;
    int E = in_sizes[1] / 2;
    int G = out_size;
    int nb = (N + 255) >> 8;

    char* ws = (char*)d_ws;
    size_t off = 0;
    auto alloc = [&](size_t bytes) -> void* {
        void* p = ws + off;
        off += (bytes + 255) & ~(size_t)255;
        return p;
    };
    __half* bufA     = (__half*)alloc((size_t)N * FEAT * 2);
    __half* bufB     = (__half*)alloc((size_t)N * FEAT * 2);
    __half* Wt1      = (__half*)alloc((size_t)FEAT * FEAT * 2);
    __half* Wt2      = (__half*)alloc((size_t)FEAT * FEAT * 2);
    float* dinv      = (float*)alloc((size_t)N * 4);
    int*   deg       = (int*)alloc((size_t)N * 4);
    int*   rowstart  = (int*)alloc((size_t)N * 4);
    int*   bsum      = (int*)alloc((size_t)nb * 4);
    int*   bucket_cnt    = (int*)alloc((size_t)(nb + 1) * 4);
    int*   bucket_base   = (int*)alloc((size_t)(nb + 1) * 4);
    int*   bucket_cursor = (int*)alloc((size_t)nb * 4);
    unsigned* binned = (unsigned*)alloc((size_t)E * 4);
    int*   soff      = (int*)alloc((size_t)E * 4);
    float* coef      = (float*)alloc((size_t)E * 4);

    // ---- CSR build (rebuilt every call; ws is re-poisoned) ----
    hipMemsetAsync(bucket_cnt, 0, (size_t)nb * 4, stream);
    k_bucket_count<<<256, 256, 0, stream>>>(ei + E, E, bucket_cnt, nb);
    k_scan_buckets<<<1, 512, 0, stream>>>(bucket_cnt, nb, bucket_base, bucket_cursor, E);
    int chunk = (E + 127) / 128;
    k_bin_fill<<<128, 256, 0, stream>>>(ei, E, chunk, bucket_cursor, binned, nb);
    k_bucket_deg<<<nb, 256, 0, stream>>>(binned, bucket_base, N, deg);
    block_sum<<<nb, 256, 0, stream>>>(deg, N, bsum);
    scan_bsum<<<1, 1024, 0, stream>>>(bsum, nb);
    make_offsets<<<nb, 256, 0, stream>>>(deg, bsum, N, rowstart, dinv);
    k_csr_fill<<<nb, 256, 0, stream>>>(binned, bucket_base, rowstart, dinv, N, soff, coef);

    // W transposes (cheap; overlap-friendly)
    k_wt<<<32, 256, 0, stream>>>(W1, Wt1);
    k_wt<<<32, 256, 0, stream>>>(W2, Wt2);

    int gemm_grid = (N + 63) / 64;
    int agg_grid  = (N + 3) / 4;

    // Layer 1
    gemm_mfma<float><<<gemm_grid, 256, 0, stream>>>(x, Wt1, bufA, N);
    agg_relu<<<agg_grid, 256, 0, stream>>>(bufA, dinv, rowstart, deg, soff, coef, b1, bufB, N);
    // Layer 2
    gemm_mfma<__half><<<gemm_grid, 256, 0, stream>>>(bufB, Wt2, bufA, N);
    agg_relu<<<agg_grid, 256, 0, stream>>>(bufA, dinv, rowstart, deg, soff, coef, b2, bufB, N);
    // Pool + head
    pool_out<<<G, 256, 0, stream>>>(bufB, batch, N, Wout, bout, (float*)d_out);
}